// Round 2
// baseline (1708.138 us; speedup 1.0000x reference)
//
#include <hip/hip_runtime.h>
#include <hip/hip_bf16.h>

#define NN 50000
#define NE 800000
#define NET (NE + NN)

static inline int imin(int a, int b) { return a < b ? a : b; }

// ---------------- CSR build (graph constant across layers) ----------------
__global__ void k_count(const int* __restrict__ edst, int* __restrict__ counts) {
    int e = blockIdx.x * blockDim.x + threadIdx.x;
    if (e >= NET) return;
    int d = (e < NE) ? edst[e] : (e - NE);   // self loops appended
    atomicAdd(&counts[d], 1);
}

__global__ __launch_bounds__(1024) void k_scan(const int* __restrict__ counts,
                                               int* __restrict__ offs, int* __restrict__ cursor) {
    __shared__ int sums[1024];
    const int CH = (NN + 1023) / 1024;   // 49
    int t = threadIdx.x;
    int b = t * CH;
    int s = 0;
    for (int i = 0; i < CH; ++i) { int idx = b + i; if (idx < NN) s += counts[idx]; }
    sums[t] = s;
    __syncthreads();
    for (int off = 1; off < 1024; off <<= 1) {
        int add = (t >= off) ? sums[t - off] : 0;
        __syncthreads();
        sums[t] += add;
        __syncthreads();
    }
    int run = sums[t] - s;  // exclusive prefix
    for (int i = 0; i < CH; ++i) {
        int idx = b + i;
        if (idx < NN) { offs[idx] = run; cursor[idx] = run; run += counts[idx]; }
    }
    if (t == 1023) offs[NN] = run;
}

__global__ void k_scatter(const int* __restrict__ esrc, const int* __restrict__ edst,
                          int* __restrict__ cursor, int* __restrict__ csr_src) {
    int e = blockIdx.x * blockDim.x + threadIdx.x;
    if (e >= NET) return;
    int s, d;
    if (e < NE) { s = esrc[e]; d = edst[e]; } else { s = e - NE; d = s; }
    int pos = atomicAdd(&cursor[d], 1);
    csr_src[pos] = s;
}

// ---------------- per-node attention scalars: s = h . a ----------------
__global__ void k_scalars(const float* __restrict__ h, const float* __restrict__ a_src,
                          const float* __restrict__ a_dst, float* __restrict__ s_src,
                          float* __restrict__ s_dst) {
    int node = blockIdx.x * 4 + (threadIdx.x >> 6);
    int lane = threadIdx.x & 63;
    if (node >= NN) return;
    const float* hr = h + (size_t)node * 128;
    float h0 = hr[lane], h1 = hr[lane + 64];
    float ps = h0 * a_src[lane] + h1 * a_src[lane + 64];
    float pd = h0 * a_dst[lane] + h1 * a_dst[lane + 64];
    #pragma unroll
    for (int off = 32; off > 0; off >>= 1) {
        ps += __shfl_down(ps, off);
        pd += __shfl_down(pd, off);
    }
    if (lane == 0) { s_src[node] = ps; s_dst[node] = pd; }
}

// ---------------- fused segment-softmax + aggregate + bias + leaky ----------------
// one wave per destination node; denominator and weighted sum in one pass
// (max-subtraction dropped: mathematically identical, |e| <~ 15 so no overflow in fp32)
__global__ void k_aggregate(const float* __restrict__ h, const float* __restrict__ s_src,
                            const float* __restrict__ s_dst, const int* __restrict__ offs,
                            const int* __restrict__ csr_src, const float* __restrict__ bias,
                            float* __restrict__ xout) {
    int node = blockIdx.x * 4 + (threadIdx.x >> 6);
    int lane = threadIdx.x & 63;
    if (node >= NN) return;
    int p = offs[node], pe = offs[node + 1];
    float sd = s_dst[node];
    float den = 0.f, acc0 = 0.f, acc1 = 0.f;
    for (; p < pe; ++p) {
        int src = csr_src[p];                 // broadcast read (all lanes same addr)
        float e = s_src[src] + sd;
        e = (e > 0.f) ? e : 0.2f * e;         // leaky_relu(e, 0.2)
        float wgt = __expf(e);
        den += wgt;
        const float* hr = h + (size_t)src * 128;
        acc0 += wgt * hr[lane];
        acc1 += wgt * hr[lane + 64];
    }
    float inv = 1.f / den;                    // self-loop guarantees den > 0
    float v0 = acc0 * inv + bias[lane];
    float v1 = acc1 * inv + bias[lane + 64];
    xout[(size_t)node * 128 + lane]      = (v0 > 0.f) ? v0 : 0.2f * v0;
    xout[(size_t)node * 128 + lane + 64] = (v1 > 0.f) ? v1 : 0.2f * v1;
}

// ---------------- generic fp32 tiled GEMM: C = act(A[MxK] @ B[KxN] + bias) ----------------
// BM=BN=64, BK=16, 256 threads, 4x4 micro-tile. K must be a multiple of 16.
#define BM 64
#define BN 64
#define BK 16
__global__ __launch_bounds__(256) void k_gemm(
    const float* __restrict__ A, const float* __restrict__ B,
    const float* __restrict__ bias, float* __restrict__ C,
    int M, int N, int K, int act)
{
    __shared__ float As[BK][BM + 1];
    __shared__ float Bs[BK][BN];
    int tid = threadIdx.x;
    int row0 = blockIdx.x * BM;
    int col0 = blockIdx.y * BN;
    int tm = (tid >> 4) * 4;
    int tn = (tid & 15) * 4;
    int ar = tid >> 2;            // A-tile row 0..63
    int ak = (tid & 3) * 4;       // A-tile k   0,4,8,12
    int bk = tid >> 4;            // B-tile k   0..15
    int bn = (tid & 15) * 4;      // B-tile col 0..60

    float acc[4][4];
    #pragma unroll
    for (int i = 0; i < 4; i++)
        #pragma unroll
        for (int j = 0; j < 4; j++) acc[i][j] = 0.f;

    for (int k0 = 0; k0 < K; k0 += BK) {
        float4 av = make_float4(0.f, 0.f, 0.f, 0.f);
        int arow = row0 + ar;
        if (arow < M) av = *(const float4*)(A + (size_t)arow * K + k0 + ak);
        As[ak + 0][ar] = av.x; As[ak + 1][ar] = av.y;
        As[ak + 2][ar] = av.z; As[ak + 3][ar] = av.w;

        int gcol = col0 + bn;
        const float* Brow = B + (size_t)(k0 + bk) * N;
        float4 bv = make_float4(0.f, 0.f, 0.f, 0.f);
        if (gcol + 3 < N) {
            bv = *(const float4*)(Brow + gcol);
        } else {
            if (gcol + 0 < N) bv.x = Brow[gcol + 0];
            if (gcol + 1 < N) bv.y = Brow[gcol + 1];
            if (gcol + 2 < N) bv.z = Brow[gcol + 2];
        }
        *(float4*)&Bs[bk][bn] = bv;
        __syncthreads();

        #pragma unroll
        for (int k = 0; k < BK; ++k) {
            float a0 = As[k][tm + 0], a1 = As[k][tm + 1];
            float a2 = As[k][tm + 2], a3 = As[k][tm + 3];
            float4 b = *(float4*)&Bs[k][tn];
            acc[0][0] += a0 * b.x; acc[0][1] += a0 * b.y; acc[0][2] += a0 * b.z; acc[0][3] += a0 * b.w;
            acc[1][0] += a1 * b.x; acc[1][1] += a1 * b.y; acc[1][2] += a1 * b.z; acc[1][3] += a1 * b.w;
            acc[2][0] += a2 * b.x; acc[2][1] += a2 * b.y; acc[2][2] += a2 * b.z; acc[2][3] += a2 * b.w;
            acc[3][0] += a3 * b.x; acc[3][1] += a3 * b.y; acc[3][2] += a3 * b.z; acc[3][3] += a3 * b.w;
        }
        __syncthreads();
    }

    #pragma unroll
    for (int i = 0; i < 4; i++) {
        int row = row0 + tm + i;
        if (row >= M) continue;
        #pragma unroll
        for (int j = 0; j < 4; j++) {
            int col = col0 + tn + j;
            if (col >= N) continue;
            float v = acc[i][j];
            if (bias) v += bias[col];
            if (act == 1) v = (v > 0.f) ? v : 0.f;
            C[(size_t)row * N + col] = v;
        }
    }
}

extern "C" void kernel_launch(void* const* d_in, const int* in_sizes, int n_in,
                              void* d_out, int out_size, void* d_ws, size_t ws_size,
                              hipStream_t stream) {
    // All float tensors are fp32 (reference dtype); edge_index is int32.
    const float* x    = (const float*)d_in[0];
    const int*   eidx = (const int*)d_in[1];
    const float* cW   = (const float*)d_in[2];
    const float* caS  = (const float*)d_in[3];
    const float* caD  = (const float*)d_in[4];
    const float* cB   = (const float*)d_in[5];
    const float* W0   = (const float*)d_in[6];
    const float* b0   = (const float*)d_in[7];
    const float* W1   = (const float*)d_in[8];
    const float* b1   = (const float*)d_in[9];
    const float* W2   = (const float*)d_in[10];
    const float* b2   = (const float*)d_in[11];
    const float* Wo   = (const float*)d_in[12];
    const float* bo   = (const float*)d_in[13];
    (void)in_sizes; (void)n_in; (void)out_size;

    const int* esrc = eidx;
    const int* edst = eidx + NE;
    float* out = (float*)d_out;

    // ---- workspace bump allocator (256B aligned) ----
    char* w = (char*)d_ws;
    auto alloc = [&](size_t bytes) -> char* {
        char* p = w;
        w += (bytes + 255) & ~(size_t)255;
        return p;
    };
    float* xbuf   = (float*)alloc((size_t)NN * 128 * 4);   // GAT layer outputs
    float* hbuf   = (float*)alloc((size_t)NN * 128 * 4);   // h = x @ W
    float* ssrc   = (float*)alloc((size_t)NN * 4);
    float* sdst   = (float*)alloc((size_t)NN * 4);
    int*   counts = (int*)  alloc((size_t)NN * 4);
    int*   offs   = (int*)  alloc((size_t)(NN + 1) * 4);
    int*   cursor = (int*)  alloc((size_t)NN * 4);
    int*   csr    = (int*)  alloc((size_t)NET * 4);

    // MLP ping-pong buffers sized from remaining workspace
    size_t used = (size_t)(w - (char*)d_ws);
    size_t rem = (ws_size > used) ? (ws_size - used) : 0;
    int chunk = (int)(rem / (2 * 512 * sizeof(float)));
    if (chunk > NN) chunk = NN;
    if (chunk > 64) chunk &= ~63;
    if (chunk < 1) chunk = 1;
    float* Y0 = (float*)alloc((size_t)chunk * 512 * 4);
    float* Y1 = (float*)alloc((size_t)chunk * 512 * 4);

    auto gemm = [&](const float* A, const float* B, const float* bias, float* C,
                    int M, int N, int K, int act) {
        dim3 g((M + BM - 1) / BM, (N + BN - 1) / BN);
        k_gemm<<<g, 256, 0, stream>>>(A, B, bias, C, M, N, K, act);
    };

    // ---- build CSR once (graph identical across layers) ----
    hipMemsetAsync(counts, 0, (size_t)NN * 4, stream);
    int eblocks = (NET + 255) / 256;
    k_count  <<<eblocks, 256, 0, stream>>>(edst, counts);
    k_scan   <<<1, 1024, 0, stream>>>(counts, offs, cursor);
    k_scatter<<<eblocks, 256, 0, stream>>>(esrc, edst, cursor, csr);

    // ---- 3 GAT layers ----
    for (int L = 0; L < 3; ++L) {
        const float* xin = (L == 0) ? x : xbuf;
        gemm(xin, cW + (size_t)L * 128 * 128, nullptr, hbuf, NN, 128, 128, 0);
        k_scalars  <<<NN / 4, 256, 0, stream>>>(hbuf, caS + L * 128, caD + L * 128, ssrc, sdst);
        k_aggregate<<<NN / 4, 256, 0, stream>>>(hbuf, ssrc, sdst, offs, csr, cB + L * 128, xbuf);
    }

    // ---- MLP head (chunked over nodes) ----
    for (int m0 = 0; m0 < NN; m0 += chunk) {
        int cm = imin(chunk, NN - m0);
        gemm(xbuf + (size_t)m0 * 128, W0, b0, Y0, cm, 512, 128, 1);
        gemm(Y0, W1, b1, Y1, cm, 512, 512, 1);
        gemm(Y1, W2, b2, Y0, cm, 512, 512, 1);
        gemm(Y0, Wo, bo, out + (size_t)m0 * 4, cm, 4, 512, 0);
    }
}

// Round 4
// 1589.791 us; speedup vs baseline: 1.0744x; 1.0744x over previous
//
#include <hip/hip_runtime.h>
#include <hip/hip_bf16.h>

#define NN 50000
#define NE 800000
#define NET (NE + NN)

static inline int imin(int a, int b) { return a < b ? a : b; }

// ---------------- CSR build (graph constant across layers) ----------------
__global__ void k_count(const int* __restrict__ edst, int* __restrict__ counts) {
    int e = blockIdx.x * blockDim.x + threadIdx.x;
    if (e >= NET) return;
    int d = (e < NE) ? edst[e] : (e - NE);   // self loops appended
    atomicAdd(&counts[d], 1);
}

__global__ __launch_bounds__(1024) void k_scan(const int* __restrict__ counts,
                                               int* __restrict__ offs, int* __restrict__ cursor) {
    __shared__ int sums[1024];
    const int CH = (NN + 1023) / 1024;   // 49
    int t = threadIdx.x;
    int b = t * CH;
    int s = 0;
    for (int i = 0; i < CH; ++i) { int idx = b + i; if (idx < NN) s += counts[idx]; }
    sums[t] = s;
    __syncthreads();
    for (int off = 1; off < 1024; off <<= 1) {
        int add = (t >= off) ? sums[t - off] : 0;
        __syncthreads();
        sums[t] += add;
        __syncthreads();
    }
    int run = sums[t] - s;  // exclusive prefix
    for (int i = 0; i < CH; ++i) {
        int idx = b + i;
        if (idx < NN) { offs[idx] = run; cursor[idx] = run; run += counts[idx]; }
    }
    if (t == 1023) offs[NN] = run;
}

__global__ void k_scatter(const int* __restrict__ esrc, const int* __restrict__ edst,
                          int* __restrict__ cursor, int* __restrict__ csr_src) {
    int e = blockIdx.x * blockDim.x + threadIdx.x;
    if (e >= NET) return;
    int s, d;
    if (e < NE) { s = esrc[e]; d = edst[e]; } else { s = e - NE; d = s; }
    int pos = atomicAdd(&cursor[d], 1);
    csr_src[pos] = s;
}

// ---------------- per-node attention scalars: s = h . a ----------------
__global__ void k_scalars(const float* __restrict__ h, const float* __restrict__ a_src,
                          const float* __restrict__ a_dst, float* __restrict__ s_src,
                          float* __restrict__ s_dst) {
    int node = blockIdx.x * 4 + (threadIdx.x >> 6);
    int lane = threadIdx.x & 63;
    if (node >= NN) return;
    const float* hr = h + (size_t)node * 128;
    float h0 = hr[lane], h1 = hr[lane + 64];
    float ps = h0 * a_src[lane] + h1 * a_src[lane + 64];
    float pd = h0 * a_dst[lane] + h1 * a_dst[lane + 64];
    #pragma unroll
    for (int off = 32; off > 0; off >>= 1) {
        ps += __shfl_down(ps, off);
        pd += __shfl_down(pd, off);
    }
    if (lane == 0) { s_src[node] = ps; s_dst[node] = pd; }
}

// ---------------- fused segment-softmax + aggregate + bias + leaky ----------------
__global__ void k_aggregate(const float* __restrict__ h, const float* __restrict__ s_src,
                            const float* __restrict__ s_dst, const int* __restrict__ offs,
                            const int* __restrict__ csr_src, const float* __restrict__ bias,
                            float* __restrict__ xout) {
    int node = blockIdx.x * 4 + (threadIdx.x >> 6);
    int lane = threadIdx.x & 63;
    if (node >= NN) return;
    int p = offs[node], pe = offs[node + 1];
    float sd = s_dst[node];
    float den = 0.f, acc0 = 0.f, acc1 = 0.f;
    for (; p < pe; ++p) {
        int src = csr_src[p];                 // broadcast read
        float e = s_src[src] + sd;
        e = (e > 0.f) ? e : 0.2f * e;         // leaky_relu(e, 0.2)
        float wgt = __expf(e);
        den += wgt;
        const float* hr = h + (size_t)src * 128;
        acc0 += wgt * hr[lane];
        acc1 += wgt * hr[lane + 64];
    }
    float inv = 1.f / den;                    // self-loop guarantees den > 0
    float v0 = acc0 * inv + bias[lane];
    float v1 = acc1 * inv + bias[lane + 64];
    xout[(size_t)node * 128 + lane]      = (v0 > 0.f) ? v0 : 0.2f * v0;
    xout[(size_t)node * 128 + lane + 64] = (v1 > 0.f) ? v1 : 0.2f * v1;
}

// ---------------- fp32 GEMM: 128x128 tile, 256 threads, 8x8 micro (2x2 of 4x4) ----
// Requires N % 128 == 0, K % 16 == 0. M arbitrary (guarded).
// blockIdx.x = N-tile (so consecutive blocks share the A panel -> L2/L3 reuse),
// blockIdx.y = M-tile.
#define TBM 128
#define TBN 128
#define TBK 16
__global__ __launch_bounds__(256) void k_gemm128(
    const float* __restrict__ A, const float* __restrict__ B,
    const float* __restrict__ bias, float* __restrict__ C,
    int M, int N, int K, int act)
{
    __shared__ float As[TBK][TBM + 4];   // +4 pad: keeps 16B align, breaks conflicts
    __shared__ float Bs[TBK][TBN];
    int tid  = threadIdx.x;
    int col0 = blockIdx.x * TBN;
    int row0 = blockIdx.y * TBM;

    int tm4 = (tid >> 4) * 4;    // 0..60
    int tn4 = (tid & 15) * 4;    // 0..60

    // staging coords
    int ar = tid >> 2;            // A row in tile (0..63; +64 on rep)
    int ac = (tid & 3) * 4;       // A k-col (0,4,8,12)
    int bk = tid >> 4;            // B k-row (0..15)
    int bn = (tid & 15) * 4;      // B col (0..60; +64 on rep)

    float acc[8][8];
    #pragma unroll
    for (int i = 0; i < 8; i++)
        #pragma unroll
        for (int j = 0; j < 8; j++) acc[i][j] = 0.f;

    for (int k0 = 0; k0 < K; k0 += TBK) {
        #pragma unroll
        for (int rep = 0; rep < 2; ++rep) {
            int r = ar + rep * 64;
            int grow = row0 + r;
            float4 av = make_float4(0.f, 0.f, 0.f, 0.f);
            if (grow < M) av = *(const float4*)(A + (size_t)grow * K + k0 + ac);
            As[ac + 0][r] = av.x; As[ac + 1][r] = av.y;
            As[ac + 2][r] = av.z; As[ac + 3][r] = av.w;

            int n = bn + rep * 64;
            float4 bv = *(const float4*)(B + (size_t)(k0 + bk) * N + col0 + n);
            *(float4*)&Bs[bk][n] = bv;
        }
        __syncthreads();

        #pragma unroll
        for (int k = 0; k < TBK; ++k) {
            float4 a0 = *(float4*)&As[k][tm4];
            float4 a1 = *(float4*)&As[k][tm4 + 64];
            float4 b0 = *(float4*)&Bs[k][tn4];
            float4 b1 = *(float4*)&Bs[k][tn4 + 64];
            float av[8] = {a0.x, a0.y, a0.z, a0.w, a1.x, a1.y, a1.z, a1.w};
            float bv[8] = {b0.x, b0.y, b0.z, b0.w, b1.x, b1.y, b1.z, b1.w};
            #pragma unroll
            for (int i = 0; i < 8; i++)
                #pragma unroll
                for (int j = 0; j < 8; j++)
                    acc[i][j] += av[i] * bv[j];
        }
        __syncthreads();
    }

    // bias for this thread's two column quads
    float4 bias0 = make_float4(0.f, 0.f, 0.f, 0.f), bias1 = bias0;
    if (bias) {
        bias0 = *(const float4*)(bias + col0 + tn4);
        bias1 = *(const float4*)(bias + col0 + tn4 + 64);
    }

    #pragma unroll
    for (int i = 0; i < 8; i++) {
        int row = row0 + tm4 + (i < 4 ? i : 60 + i);
        if (row >= M) continue;
        #pragma unroll
        for (int jg = 0; jg < 2; jg++) {
            float4 bb = jg ? bias1 : bias0;
            float4 v;
            v.x = acc[i][jg * 4 + 0] + bb.x;
            v.y = acc[i][jg * 4 + 1] + bb.y;
            v.z = acc[i][jg * 4 + 2] + bb.z;
            v.w = acc[i][jg * 4 + 3] + bb.w;
            if (act == 1) {
                v.x = v.x > 0.f ? v.x : 0.f;
                v.y = v.y > 0.f ? v.y : 0.f;
                v.z = v.z > 0.f ? v.z : 0.f;
                v.w = v.w > 0.f ? v.w : 0.f;
            }
            *(float4*)(C + (size_t)row * N + col0 + tn4 + jg * 64) = v;
        }
    }
}

// ---------------- head: out[M x 4] = Y[M x 512] @ Wo[512 x 4] + bo ----------------
// one wave per node; Wo rows read from global (L2-resident, broadcast across blocks)
__global__ __launch_bounds__(256) void k_head(const float* __restrict__ Y,
                                              const float* __restrict__ Wo,
                                              const float* __restrict__ bo,
                                              float* __restrict__ out, int M) {
    int node = blockIdx.x * 4 + (threadIdx.x >> 6);
    int lane = threadIdx.x & 63;
    if (node >= M) return;
    const float* y = Y + (size_t)node * 512 + lane * 8;
    float4 ya = *(const float4*)y;
    float4 yb = *(const float4*)(y + 4);
    float yv[8] = {ya.x, ya.y, ya.z, ya.w, yb.x, yb.y, yb.z, yb.w};
    float a0 = 0.f, a1 = 0.f, a2 = 0.f, a3 = 0.f;
    #pragma unroll
    for (int i = 0; i < 8; i++) {
        float4 wv = *(const float4*)(Wo + (size_t)(lane * 8 + i) * 4);
        a0 += yv[i] * wv.x; a1 += yv[i] * wv.y;
        a2 += yv[i] * wv.z; a3 += yv[i] * wv.w;
    }
    #pragma unroll
    for (int off = 32; off > 0; off >>= 1) {
        a0 += __shfl_down(a0, off);
        a1 += __shfl_down(a1, off);
        a2 += __shfl_down(a2, off);
        a3 += __shfl_down(a3, off);
    }
    if (lane == 0) {
        float4 o;
        o.x = a0 + bo[0]; o.y = a1 + bo[1]; o.z = a2 + bo[2]; o.w = a3 + bo[3];
        *(float4*)(out + (size_t)node * 4) = o;
    }
}

extern "C" void kernel_launch(void* const* d_in, const int* in_sizes, int n_in,
                              void* d_out, int out_size, void* d_ws, size_t ws_size,
                              hipStream_t stream) {
    const float* x    = (const float*)d_in[0];
    const int*   eidx = (const int*)d_in[1];
    const float* cW   = (const float*)d_in[2];
    const float* caS  = (const float*)d_in[3];
    const float* caD  = (const float*)d_in[4];
    const float* cB   = (const float*)d_in[5];
    const float* W0   = (const float*)d_in[6];
    const float* b0   = (const float*)d_in[7];
    const float* W1   = (const float*)d_in[8];
    const float* b1   = (const float*)d_in[9];
    const float* W2   = (const float*)d_in[10];
    const float* b2   = (const float*)d_in[11];
    const float* Wo   = (const float*)d_in[12];
    const float* bo   = (const float*)d_in[13];
    (void)in_sizes; (void)n_in; (void)out_size;

    const int* esrc = eidx;
    const int* edst = eidx + NE;
    float* out = (float*)d_out;

    // ---- workspace bump allocator (256B aligned) ----
    char* w = (char*)d_ws;
    auto alloc = [&](size_t bytes) -> char* {
        char* p = w;
        w += (bytes + 255) & ~(size_t)255;
        return p;
    };
    float* xbuf   = (float*)alloc((size_t)NN * 128 * 4);   // GAT layer outputs
    float* hbuf   = (float*)alloc((size_t)NN * 128 * 4);   // h = x @ W
    float* ssrc   = (float*)alloc((size_t)NN * 4);
    float* sdst   = (float*)alloc((size_t)NN * 4);
    int*   counts = (int*)  alloc((size_t)NN * 4);
    int*   offs   = (int*)  alloc((size_t)(NN + 1) * 4);
    int*   cursor = (int*)  alloc((size_t)NN * 4);
    int*   csr    = (int*)  alloc((size_t)NET * 4);

    // MLP ping-pong buffers sized from remaining workspace
    size_t used = (size_t)(w - (char*)d_ws);
    size_t rem = (ws_size > used) ? (ws_size - used) : 0;
    int chunk = (int)(rem / (2 * 512 * sizeof(float)));
    if (chunk > NN) chunk = NN;
    if (chunk > 128) chunk &= ~127;
    if (chunk < 1) chunk = 1;
    float* Y0 = (float*)alloc((size_t)chunk * 512 * 4);
    float* Y1 = (float*)alloc((size_t)chunk * 512 * 4);

    auto gemm = [&](const float* A, const float* B, const float* bias, float* C,
                    int M, int N, int K, int act) {
        dim3 g(N / TBN, (M + TBM - 1) / TBM);
        k_gemm128<<<g, 256, 0, stream>>>(A, B, bias, C, M, N, K, act);
    };

    // ---- build CSR once ----
    hipMemsetAsync(counts, 0, (size_t)NN * 4, stream);
    int eblocks = (NET + 255) / 256;
    k_count  <<<eblocks, 256, 0, stream>>>(edst, counts);
    k_scan   <<<1, 1024, 0, stream>>>(counts, offs, cursor);
    k_scatter<<<eblocks, 256, 0, stream>>>(esrc, edst, cursor, csr);

    // ---- 3 GAT layers ----
    for (int L = 0; L < 3; ++L) {
        const float* xin = (L == 0) ? x : xbuf;
        gemm(xin, cW + (size_t)L * 128 * 128, nullptr, hbuf, NN, 128, 128, 0);
        k_scalars  <<<NN / 4, 256, 0, stream>>>(hbuf, caS + L * 128, caD + L * 128, ssrc, sdst);
        k_aggregate<<<NN / 4, 256, 0, stream>>>(hbuf, ssrc, sdst, offs, csr, cB + L * 128, xbuf);
    }

    // ---- MLP head (chunked over nodes) ----
    for (int m0 = 0; m0 < NN; m0 += chunk) {
        int cm = imin(chunk, NN - m0);
        gemm(xbuf + (size_t)m0 * 128, W0, b0, Y0, cm, 512, 128, 1);
        gemm(Y0, W1, b1, Y1, cm, 512, 512, 1);
        gemm(Y1, W2, b2, Y0, cm, 512, 512, 1);
        k_head<<<(cm + 3) / 4, 256, 0, stream>>>(Y0, Wo, bo, out + (size_t)m0 * 4, cm);
    }
}

// Round 5
// 1122.291 us; speedup vs baseline: 1.5220x; 1.4166x over previous
//
#include <hip/hip_runtime.h>
#include <hip/hip_bf16.h>

#define NN 50000
#define NE 800000
#define NET (NE + NN)

static inline int imin(int a, int b) { return a < b ? a : b; }

typedef _Float16 half8 __attribute__((ext_vector_type(8)));
typedef float f32x4 __attribute__((ext_vector_type(4)));

// ---------------- CSR build (graph constant across layers) ----------------
__global__ void k_count(const int* __restrict__ edst, int* __restrict__ counts) {
    int e = blockIdx.x * blockDim.x + threadIdx.x;
    if (e >= NET) return;
    int d = (e < NE) ? edst[e] : (e - NE);   // self loops appended
    atomicAdd(&counts[d], 1);
}

__global__ __launch_bounds__(1024) void k_scan(const int* __restrict__ counts,
                                               int* __restrict__ offs, int* __restrict__ cursor) {
    __shared__ int sums[1024];
    const int CH = (NN + 1023) / 1024;   // 49
    int t = threadIdx.x;
    int b = t * CH;
    int s = 0;
    for (int i = 0; i < CH; ++i) { int idx = b + i; if (idx < NN) s += counts[idx]; }
    sums[t] = s;
    __syncthreads();
    for (int off = 1; off < 1024; off <<= 1) {
        int add = (t >= off) ? sums[t - off] : 0;
        __syncthreads();
        sums[t] += add;
        __syncthreads();
    }
    int run = sums[t] - s;  // exclusive prefix
    for (int i = 0; i < CH; ++i) {
        int idx = b + i;
        if (idx < NN) { offs[idx] = run; cursor[idx] = run; run += counts[idx]; }
    }
    if (t == 1023) offs[NN] = run;
}

__global__ void k_scatter(const int* __restrict__ esrc, const int* __restrict__ edst,
                          int* __restrict__ cursor, int* __restrict__ csr_src) {
    int e = blockIdx.x * blockDim.x + threadIdx.x;
    if (e >= NET) return;
    int s, d;
    if (e < NE) { s = esrc[e]; d = edst[e]; } else { s = e - NE; d = s; }
    int pos = atomicAdd(&cursor[d], 1);
    csr_src[pos] = s;
}

// ---------------- split fp32 -> f16 hi/lo pair ----------------
__global__ void k_split(const float* __restrict__ in, _Float16* __restrict__ hi,
                        _Float16* __restrict__ lo, int n) {
    int i = blockIdx.x * blockDim.x + threadIdx.x;
    int st = gridDim.x * blockDim.x;
    for (; i < n; i += st) {
        float v = in[i];
        _Float16 h = (_Float16)v;
        hi[i] = h;
        lo[i] = (_Float16)(v - (float)h);
    }
}

// ---------------- transpose + split weights: W[K][N] -> T[N][K] hi/lo ----------------
__global__ void k_prepw(const float* __restrict__ W, _Float16* __restrict__ Th,
                        _Float16* __restrict__ Tl, int K, int N) {
    int i = blockIdx.x * blockDim.x + threadIdx.x;
    if (i >= K * N) return;
    int k = i / N, n = i % N;          // coalesced read
    float v = W[i];
    _Float16 h = (_Float16)v;
    Th[(size_t)n * K + k] = h;
    Tl[(size_t)n * K + k] = (_Float16)(v - (float)h);
}

// ---------------- per-node attention scalars: s = h . a ----------------
__global__ void k_scalars(const float* __restrict__ h, const float* __restrict__ a_src,
                          const float* __restrict__ a_dst, float* __restrict__ s_src,
                          float* __restrict__ s_dst) {
    int node = blockIdx.x * 4 + (threadIdx.x >> 6);
    int lane = threadIdx.x & 63;
    if (node >= NN) return;
    const float* hr = h + (size_t)node * 128;
    float h0 = hr[lane], h1 = hr[lane + 64];
    float ps = h0 * a_src[lane] + h1 * a_src[lane + 64];
    float pd = h0 * a_dst[lane] + h1 * a_dst[lane + 64];
    #pragma unroll
    for (int off = 32; off > 0; off >>= 1) {
        ps += __shfl_down(ps, off);
        pd += __shfl_down(pd, off);
    }
    if (lane == 0) { s_src[node] = ps; s_dst[node] = pd; }
}

// ---------------- fused segment-softmax + aggregate + bias + leaky ----------------
// output written as f16 hi/lo pair (next consumer is the MFMA GEMM)
__global__ void k_aggregate(const float* __restrict__ h, const float* __restrict__ s_src,
                            const float* __restrict__ s_dst, const int* __restrict__ offs,
                            const int* __restrict__ csr_src, const float* __restrict__ bias,
                            _Float16* __restrict__ xh, _Float16* __restrict__ xl) {
    int node = blockIdx.x * 4 + (threadIdx.x >> 6);
    int lane = threadIdx.x & 63;
    if (node >= NN) return;
    int p = offs[node], pe = offs[node + 1];
    float sd = s_dst[node];
    float den = 0.f, acc0 = 0.f, acc1 = 0.f;
    for (; p < pe; ++p) {
        int src = csr_src[p];                 // broadcast read
        float e = s_src[src] + sd;
        e = (e > 0.f) ? e : 0.2f * e;         // leaky_relu(e, 0.2)
        float wgt = __expf(e);
        den += wgt;
        const float* hr = h + (size_t)src * 128;
        acc0 += wgt * hr[lane];
        acc1 += wgt * hr[lane + 64];
    }
    float inv = 1.f / den;                    // self-loop guarantees den > 0
    float v0 = acc0 * inv + bias[lane];
    float v1 = acc1 * inv + bias[lane + 64];
    v0 = (v0 > 0.f) ? v0 : 0.2f * v0;
    v1 = (v1 > 0.f) ? v1 : 0.2f * v1;
    _Float16 h0 = (_Float16)v0, h1 = (_Float16)v1;
    size_t base = (size_t)node * 128;
    xh[base + lane]      = h0;
    xl[base + lane]      = (_Float16)(v0 - (float)h0);
    xh[base + lane + 64] = h1;
    xl[base + lane + 64] = (_Float16)(v1 - (float)h1);
}

// ---------------- split-f16 MFMA GEMM ----------------
// C[M][N] = act(A[M][K] @ B^T[N][K] + bias), where A,B given as f16 hi/lo pairs and
// A·B ≈ Ahi·Bhi + Ahi·Blo + Alo·Bhi (fp32 accumulate in MFMA).
// 128x128 tile, 4 waves (2x2), each wave 64x64 = 4x4 of 16x16x32 MFMA. BK=32.
// Requires K % 32 == 0, N % 128 == 0. M guarded.
// out: split != 0 -> write Chi/Clo f16 pair; else write Cf fp32.
__global__ __launch_bounds__(256) void k_mgemm(
    const _Float16* __restrict__ Ahi, const _Float16* __restrict__ Alo,
    const _Float16* __restrict__ Bhi, const _Float16* __restrict__ Blo,
    const float* __restrict__ bias, float* __restrict__ Cf,
    _Float16* __restrict__ Chi, _Float16* __restrict__ Clo,
    int M, int N, int K, int relu, int split)
{
    // row stride 40 f16 (80B): 16B-aligned, banks land 2-way max (free)
    __shared__ _Float16 sA[2][128][40];
    __shared__ _Float16 sB[2][128][40];

    int t = threadIdx.x;
    int col0 = blockIdx.x * 128;      // N-tile fastest -> consecutive blocks share A panel
    int row0 = blockIdx.y * 128;

    int w = t >> 6, lane = t & 63;
    int wm = (w & 1) * 64, wn = (w >> 1) * 64;
    int fr = lane & 15;               // m (A) / n (B,C)
    int fq = lane >> 4;               // quad: k-group for A/B, row-group for C

    int srow = t >> 2;                // 0..63
    int scol = (t & 3) * 8;           // 0,8,16,24

    f32x4 acc[4][4];
    #pragma unroll
    for (int i = 0; i < 4; i++)
        #pragma unroll
        for (int j = 0; j < 4; j++) acc[i][j] = (f32x4){0.f, 0.f, 0.f, 0.f};

    for (int k0 = 0; k0 < K; k0 += 32) {
        if (k0) __syncthreads();
        #pragma unroll
        for (int c = 0; c < 2; ++c) {
            int r = srow + c * 64;
            int ga = row0 + r;
            half8 vh = {}, vl = {};
            if (ga < M) {
                vh = *(const half8*)(Ahi + (size_t)ga * K + k0 + scol);
                vl = *(const half8*)(Alo + (size_t)ga * K + k0 + scol);
            }
            *(half8*)&sA[0][r][scol] = vh;
            *(half8*)&sA[1][r][scol] = vl;
            int gb = col0 + r;        // N % 128 == 0 -> always in range
            *(half8*)&sB[0][r][scol] = *(const half8*)(Bhi + (size_t)gb * K + k0 + scol);
            *(half8*)&sB[1][r][scol] = *(const half8*)(Blo + (size_t)gb * K + k0 + scol);
        }
        __syncthreads();

        half8 bh[4], bl[4];
        #pragma unroll
        for (int ni = 0; ni < 4; ++ni) {
            bh[ni] = *(half8*)&sB[0][wn + ni * 16 + fr][fq * 8];
            bl[ni] = *(half8*)&sB[1][wn + ni * 16 + fr][fq * 8];
        }
        #pragma unroll
        for (int mi = 0; mi < 4; ++mi) {
            half8 ah = *(half8*)&sA[0][wm + mi * 16 + fr][fq * 8];
            half8 al = *(half8*)&sA[1][wm + mi * 16 + fr][fq * 8];
            #pragma unroll
            for (int ni = 0; ni < 4; ++ni) {
                acc[mi][ni] = __builtin_amdgcn_mfma_f32_16x16x32_f16(ah, bh[ni], acc[mi][ni], 0, 0, 0);
                acc[mi][ni] = __builtin_amdgcn_mfma_f32_16x16x32_f16(ah, bl[ni], acc[mi][ni], 0, 0, 0);
                acc[mi][ni] = __builtin_amdgcn_mfma_f32_16x16x32_f16(al, bh[ni], acc[mi][ni], 0, 0, 0);
            }
        }
    }

    // epilogue: C/D layout col=lane&15, row=quad*4+reg
    #pragma unroll
    for (int ni = 0; ni < 4; ++ni) {
        int gc = col0 + wn + ni * 16 + fr;
        float bv = bias ? bias[gc] : 0.f;
        #pragma unroll
        for (int mi = 0; mi < 4; ++mi) {
            #pragma unroll
            for (int r = 0; r < 4; ++r) {
                int gr = row0 + wm + mi * 16 + fq * 4 + r;
                if (gr >= M) continue;
                float v = acc[mi][ni][r] + bv;
                if (relu) v = (v > 0.f) ? v : 0.f;
                size_t idx = (size_t)gr * N + gc;
                if (split) {
                    _Float16 hh = (_Float16)v;
                    Chi[idx] = hh;
                    Clo[idx] = (_Float16)(v - (float)hh);
                } else {
                    Cf[idx] = v;
                }
            }
        }
    }
}

// ---------------- head: out[M x 4] = (Yh+Yl)[M x 512] @ Wo[512 x 4] + bo ----------------
__global__ __launch_bounds__(256) void k_head(const _Float16* __restrict__ Yh,
                                              const _Float16* __restrict__ Yl,
                                              const float* __restrict__ Wo,
                                              const float* __restrict__ bo,
                                              float* __restrict__ out, int M) {
    int node = blockIdx.x * 4 + (threadIdx.x >> 6);
    int lane = threadIdx.x & 63;
    if (node >= M) return;
    size_t base = (size_t)node * 512 + lane * 8;
    half8 hv = *(const half8*)(Yh + base);
    half8 lv = *(const half8*)(Yl + base);
    float a0 = 0.f, a1 = 0.f, a2 = 0.f, a3 = 0.f;
    #pragma unroll
    for (int i = 0; i < 8; i++) {
        float y = (float)hv[i] + (float)lv[i];
        float4 wv = *(const float4*)(Wo + (size_t)(lane * 8 + i) * 4);
        a0 += y * wv.x; a1 += y * wv.y;
        a2 += y * wv.z; a3 += y * wv.w;
    }
    #pragma unroll
    for (int off = 32; off > 0; off >>= 1) {
        a0 += __shfl_down(a0, off);
        a1 += __shfl_down(a1, off);
        a2 += __shfl_down(a2, off);
        a3 += __shfl_down(a3, off);
    }
    if (lane == 0) {
        float4 o;
        o.x = a0 + bo[0]; o.y = a1 + bo[1]; o.z = a2 + bo[2]; o.w = a3 + bo[3];
        *(float4*)(out + (size_t)node * 4) = o;
    }
}

extern "C" void kernel_launch(void* const* d_in, const int* in_sizes, int n_in,
                              void* d_out, int out_size, void* d_ws, size_t ws_size,
                              hipStream_t stream) {
    const float* x    = (const float*)d_in[0];
    const int*   eidx = (const int*)d_in[1];
    const float* cW   = (const float*)d_in[2];
    const float* caS  = (const float*)d_in[3];
    const float* caD  = (const float*)d_in[4];
    const float* cB   = (const float*)d_in[5];
    const float* W0   = (const float*)d_in[6];
    const float* b0   = (const float*)d_in[7];
    const float* W1   = (const float*)d_in[8];
    const float* b1   = (const float*)d_in[9];
    const float* W2   = (const float*)d_in[10];
    const float* b2   = (const float*)d_in[11];
    const float* Wo   = (const float*)d_in[12];
    const float* bo   = (const float*)d_in[13];
    (void)in_sizes; (void)n_in; (void)out_size;

    const int* esrc = eidx;
    const int* edst = eidx + NE;
    float* out = (float*)d_out;

    // ---- workspace bump allocator (256B aligned) ----
    char* w = (char*)d_ws;
    auto alloc = [&](size_t bytes) -> char* {
        char* p = w;
        w += (bytes + 255) & ~(size_t)255;
        return p;
    };
    _Float16* x0h  = (_Float16*)alloc((size_t)NN * 128 * 2);   // split of input x
    _Float16* x0l  = (_Float16*)alloc((size_t)NN * 128 * 2);
    _Float16* xh   = (_Float16*)alloc((size_t)NN * 128 * 2);   // GAT layer outputs (split)
    _Float16* xl   = (_Float16*)alloc((size_t)NN * 128 * 2);
    float* hbuf    = (float*)alloc((size_t)NN * 128 * 4);      // h = x @ W (fp32)
    float* ssrc    = (float*)alloc((size_t)NN * 4);
    float* sdst    = (float*)alloc((size_t)NN * 4);
    int*   counts  = (int*)  alloc((size_t)NN * 4);
    int*   offs    = (int*)  alloc((size_t)(NN + 1) * 4);
    int*   cursor  = (int*)  alloc((size_t)NN * 4);
    int*   csr     = (int*)  alloc((size_t)NET * 4);
    // transposed/split weights: T[N][K] f16 hi/lo
    _Float16* cwh  = (_Float16*)alloc(3 * 128 * 128 * 2);
    _Float16* cwl  = (_Float16*)alloc(3 * 128 * 128 * 2);
    _Float16* w0h  = (_Float16*)alloc(512 * 128 * 2);
    _Float16* w0l  = (_Float16*)alloc(512 * 128 * 2);
    _Float16* w1h  = (_Float16*)alloc(512 * 512 * 2);
    _Float16* w1l  = (_Float16*)alloc(512 * 512 * 2);
    _Float16* w2h  = (_Float16*)alloc(512 * 512 * 2);
    _Float16* w2l  = (_Float16*)alloc(512 * 512 * 2);

    // MLP ping-pong Y buffers (f16 hi/lo x2) sized from remaining workspace
    size_t used = (size_t)(w - (char*)d_ws);
    size_t rem = (ws_size > used) ? (ws_size - used) : 0;
    int chunk = (int)(rem / (4 * 512 * sizeof(_Float16)));
    if (chunk > NN) chunk = NN;
    if (chunk > 128) chunk &= ~127;
    if (chunk < 1) chunk = 1;
    _Float16* Y0h = (_Float16*)alloc((size_t)chunk * 512 * 2);
    _Float16* Y0l = (_Float16*)alloc((size_t)chunk * 512 * 2);
    _Float16* Y1h = (_Float16*)alloc((size_t)chunk * 512 * 2);
    _Float16* Y1l = (_Float16*)alloc((size_t)chunk * 512 * 2);

    auto gemm = [&](const _Float16* Ah, const _Float16* Al,
                    const _Float16* Bh, const _Float16* Bl,
                    const float* bias, float* Cf, _Float16* Ch, _Float16* Cl,
                    int M, int N, int K, int relu, int split) {
        dim3 g(N / 128, (M + 127) / 128);
        k_mgemm<<<g, 256, 0, stream>>>(Ah, Al, Bh, Bl, bias, Cf, Ch, Cl, M, N, K, relu, split);
    };

    // ---- prep: split x, transpose+split weights ----
    k_split<<<2048, 256, 0, stream>>>(x, x0h, x0l, NN * 128);
    for (int L = 0; L < 3; ++L)
        k_prepw<<<(128 * 128 + 255) / 256, 256, 0, stream>>>(
            cW + (size_t)L * 128 * 128, cwh + (size_t)L * 128 * 128, cwl + (size_t)L * 128 * 128, 128, 128);
    k_prepw<<<(128 * 512 + 255) / 256, 256, 0, stream>>>(W0, w0h, w0l, 128, 512);
    k_prepw<<<(512 * 512 + 255) / 256, 256, 0, stream>>>(W1, w1h, w1l, 512, 512);
    k_prepw<<<(512 * 512 + 255) / 256, 256, 0, stream>>>(W2, w2h, w2l, 512, 512);

    // ---- build CSR once ----
    hipMemsetAsync(counts, 0, (size_t)NN * 4, stream);
    int eblocks = (NET + 255) / 256;
    k_count  <<<eblocks, 256, 0, stream>>>(edst, counts);
    k_scan   <<<1, 1024, 0, stream>>>(counts, offs, cursor);
    k_scatter<<<eblocks, 256, 0, stream>>>(esrc, edst, cursor, csr);

    // ---- 3 GAT layers ----
    for (int L = 0; L < 3; ++L) {
        const _Float16* Ah = (L == 0) ? x0h : xh;
        const _Float16* Al = (L == 0) ? x0l : xl;
        gemm(Ah, Al, cwh + (size_t)L * 128 * 128, cwl + (size_t)L * 128 * 128,
             nullptr, hbuf, nullptr, nullptr, NN, 128, 128, 0, 0);
        k_scalars  <<<NN / 4, 256, 0, stream>>>(hbuf, caS + L * 128, caD + L * 128, ssrc, sdst);
        k_aggregate<<<NN / 4, 256, 0, stream>>>(hbuf, ssrc, sdst, offs, csr, cB + L * 128, xh, xl);
    }

    // ---- MLP head (chunked over nodes) ----
    for (int m0 = 0; m0 < NN; m0 += chunk) {
        int cm = imin(chunk, NN - m0);
        gemm(xh + (size_t)m0 * 128, xl + (size_t)m0 * 128, w0h, w0l, b0,
             nullptr, Y0h, Y0l, cm, 512, 128, 1, 1);
        gemm(Y0h, Y0l, w1h, w1l, b1, nullptr, Y1h, Y1l, cm, 512, 512, 1, 1);
        gemm(Y1h, Y1l, w2h, w2l, b2, nullptr, Y0h, Y0l, cm, 512, 512, 1, 1);
        k_head<<<(cm + 3) / 4, 256, 0, stream>>>(Y0h, Y0l, Wo, bo, out + (size_t)m0 * 4, cm);
    }
}

// Round 6
// 1007.437 us; speedup vs baseline: 1.6955x; 1.1140x over previous
//
#include <hip/hip_runtime.h>
#include <hip/hip_bf16.h>

#define NN 50000
#define NE 800000
#define NET (NE + NN)
#define SCAN_NB ((NN + 255) / 256)   // 196

static inline int imin(int a, int b) { return a < b ? a : b; }

typedef _Float16 half8 __attribute__((ext_vector_type(8)));
typedef float f32x4 __attribute__((ext_vector_type(4)));

// ---------------- CSR build (graph constant across layers) ----------------
__global__ void k_count(const int* __restrict__ edst, int* __restrict__ counts) {
    int e = blockIdx.x * blockDim.x + threadIdx.x;
    if (e >= NET) return;
    int d = (e < NE) ? edst[e] : (e - NE);   // self loops appended
    atomicAdd(&counts[d], 1);
}

// hierarchical exclusive scan of counts[NN] -> offs/cursor (3 stages)
__global__ __launch_bounds__(256) void k_scan1(const int* __restrict__ counts,
                                               int* __restrict__ part) {
    __shared__ int s[256];
    int t = threadIdx.x, i = blockIdx.x * 256 + t;
    s[t] = (i < NN) ? counts[i] : 0;
    __syncthreads();
    for (int off = 128; off > 0; off >>= 1) {
        if (t < off) s[t] += s[t + off];
        __syncthreads();
    }
    if (t == 0) part[blockIdx.x] = s[0];
}

__global__ __launch_bounds__(256) void k_scan2(int* __restrict__ part, int* __restrict__ offs) {
    __shared__ int s[256];
    int t = threadIdx.x;
    int v = (t < SCAN_NB) ? part[t] : 0;
    s[t] = v;
    __syncthreads();
    for (int off = 1; off < 256; off <<= 1) {
        int a = (t >= off) ? s[t - off] : 0;
        __syncthreads();
        s[t] += a;
        __syncthreads();
    }
    if (t < SCAN_NB) part[t] = s[t] - v;     // exclusive block offsets
    if (t == 255) offs[NN] = s[255];         // total (= NET)
}

__global__ __launch_bounds__(256) void k_scan3(const int* __restrict__ counts,
                                               const int* __restrict__ part,
                                               int* __restrict__ offs, int* __restrict__ cursor) {
    __shared__ int s[256];
    int t = threadIdx.x, i = blockIdx.x * 256 + t;
    int v = (i < NN) ? counts[i] : 0;
    s[t] = v;
    __syncthreads();
    for (int off = 1; off < 256; off <<= 1) {
        int a = (t >= off) ? s[t - off] : 0;
        __syncthreads();
        s[t] += a;
        __syncthreads();
    }
    if (i < NN) {
        int e = part[blockIdx.x] + s[t] - v;
        offs[i] = e;
        cursor[i] = e;
    }
}

__global__ void k_scatter(const int* __restrict__ esrc, const int* __restrict__ edst,
                          int* __restrict__ cursor, int* __restrict__ csr_src) {
    int e = blockIdx.x * blockDim.x + threadIdx.x;
    if (e >= NET) return;
    int s, d;
    if (e < NE) { s = esrc[e]; d = edst[e]; } else { s = e - NE; d = s; }
    int pos = atomicAdd(&cursor[d], 1);
    csr_src[pos] = s;
}

// ---------------- split fp32 -> f16 hi/lo pair ----------------
__global__ void k_split(const float* __restrict__ in, _Float16* __restrict__ hi,
                        _Float16* __restrict__ lo, int n) {
    int i = blockIdx.x * blockDim.x + threadIdx.x;
    int st = gridDim.x * blockDim.x;
    for (; i < n; i += st) {
        float v = in[i];
        _Float16 h = (_Float16)v;
        hi[i] = h;
        lo[i] = (_Float16)(v - (float)h);
    }
}

// ---------------- transpose + split weights: W[K][N] -> T[N][K] hi/lo (LDS-tiled) ----
// K, N multiples of 32 (true for all our weights). 32x8 thread tile, 256 threads.
__global__ __launch_bounds__(256) void k_prepw(const float* __restrict__ W,
                                               _Float16* __restrict__ Th,
                                               _Float16* __restrict__ Tl, int K, int N) {
    __shared__ float tile[32][33];
    int tx = threadIdx.x & 31, ty = threadIdx.x >> 5;
    int n0 = blockIdx.x * 32, k0 = blockIdx.y * 32;
    #pragma unroll
    for (int r = ty; r < 32; r += 8)
        tile[r][tx] = W[(size_t)(k0 + r) * N + n0 + tx];   // coalesced read
    __syncthreads();
    #pragma unroll
    for (int r = ty; r < 32; r += 8) {
        int n = n0 + r, k = k0 + tx;
        float v = tile[tx][r];
        _Float16 h = (_Float16)v;
        Th[(size_t)n * K + k] = h;                          // coalesced 64B segments
        Tl[(size_t)n * K + k] = (_Float16)(v - (float)h);
    }
}

// ---------------- per-node attention scalars: s = h . a ----------------
__global__ void k_scalars(const float* __restrict__ h, const float* __restrict__ a_src,
                          const float* __restrict__ a_dst, float* __restrict__ s_src,
                          float* __restrict__ s_dst) {
    int node = blockIdx.x * 4 + (threadIdx.x >> 6);
    int lane = threadIdx.x & 63;
    if (node >= NN) return;
    const float* hr = h + (size_t)node * 128;
    float h0 = hr[lane], h1 = hr[lane + 64];
    float ps = h0 * a_src[lane] + h1 * a_src[lane + 64];
    float pd = h0 * a_dst[lane] + h1 * a_dst[lane + 64];
    #pragma unroll
    for (int off = 32; off > 0; off >>= 1) {
        ps += __shfl_down(ps, off);
        pd += __shfl_down(pd, off);
    }
    if (lane == 0) { s_src[node] = ps; s_dst[node] = pd; }
}

// ---------------- fused segment-softmax + aggregate + bias + leaky ----------------
__global__ void k_aggregate(const float* __restrict__ h, const float* __restrict__ s_src,
                            const float* __restrict__ s_dst, const int* __restrict__ offs,
                            const int* __restrict__ csr_src, const float* __restrict__ bias,
                            _Float16* __restrict__ xh, _Float16* __restrict__ xl) {
    int node = blockIdx.x * 4 + (threadIdx.x >> 6);
    int lane = threadIdx.x & 63;
    if (node >= NN) return;
    int p = offs[node], pe = offs[node + 1];
    float sd = s_dst[node];
    float den = 0.f, acc0 = 0.f, acc1 = 0.f;
    for (; p < pe; ++p) {
        int src = csr_src[p];                 // broadcast read
        float e = s_src[src] + sd;
        e = (e > 0.f) ? e : 0.2f * e;         // leaky_relu(e, 0.2)
        float wgt = __expf(e);
        den += wgt;
        const float* hr = h + (size_t)src * 128;
        acc0 += wgt * hr[lane];
        acc1 += wgt * hr[lane + 64];
    }
    float inv = 1.f / den;                    // self-loop guarantees den > 0
    float v0 = acc0 * inv + bias[lane];
    float v1 = acc1 * inv + bias[lane + 64];
    v0 = (v0 > 0.f) ? v0 : 0.2f * v0;
    v1 = (v1 > 0.f) ? v1 : 0.2f * v1;
    _Float16 h0 = (_Float16)v0, h1 = (_Float16)v1;
    size_t base = (size_t)node * 128;
    xh[base + lane]      = h0;
    xl[base + lane]      = (_Float16)(v0 - (float)h0);
    xh[base + lane + 64] = h1;
    xl[base + lane + 64] = (_Float16)(v1 - (float)h1);
}

// ---------------- split-f16 MFMA GEMM ----------------
// C[M][N] = act(A[M][K] @ B^T[N][K] + bias), A,B as f16 hi/lo pairs,
// A·B ≈ Ahi·Bhi + Ahi·Blo + Alo·Bhi (fp32 MFMA accumulate).
// 128x128 tile, 4 waves (2x2), each wave 64x64 = 4x4 of 16x16x32 MFMA. BK=32.
__global__ __launch_bounds__(256) void k_mgemm(
    const _Float16* __restrict__ Ahi, const _Float16* __restrict__ Alo,
    const _Float16* __restrict__ Bhi, const _Float16* __restrict__ Blo,
    const float* __restrict__ bias, float* __restrict__ Cf,
    _Float16* __restrict__ Chi, _Float16* __restrict__ Clo,
    int M, int N, int K, int relu, int split)
{
    __shared__ _Float16 sA[2][128][40];   // stride 40: <=2-way bank aliasing (free)
    __shared__ _Float16 sB[2][128][40];

    int t = threadIdx.x;
    int col0 = blockIdx.x * 128;
    int row0 = blockIdx.y * 128;

    int w = t >> 6, lane = t & 63;
    int wm = (w & 1) * 64, wn = (w >> 1) * 64;
    int fr = lane & 15;
    int fq = lane >> 4;

    int srow = t >> 2;
    int scol = (t & 3) * 8;

    f32x4 acc[4][4];
    #pragma unroll
    for (int i = 0; i < 4; i++)
        #pragma unroll
        for (int j = 0; j < 4; j++) acc[i][j] = (f32x4){0.f, 0.f, 0.f, 0.f};

    for (int k0 = 0; k0 < K; k0 += 32) {
        if (k0) __syncthreads();
        #pragma unroll
        for (int c = 0; c < 2; ++c) {
            int r = srow + c * 64;
            int ga = row0 + r;
            half8 vh = {}, vl = {};
            if (ga < M) {
                vh = *(const half8*)(Ahi + (size_t)ga * K + k0 + scol);
                vl = *(const half8*)(Alo + (size_t)ga * K + k0 + scol);
            }
            *(half8*)&sA[0][r][scol] = vh;
            *(half8*)&sA[1][r][scol] = vl;
            int gb = col0 + r;
            *(half8*)&sB[0][r][scol] = *(const half8*)(Bhi + (size_t)gb * K + k0 + scol);
            *(half8*)&sB[1][r][scol] = *(const half8*)(Blo + (size_t)gb * K + k0 + scol);
        }
        __syncthreads();

        half8 bh[4], bl[4];
        #pragma unroll
        for (int ni = 0; ni < 4; ++ni) {
            bh[ni] = *(half8*)&sB[0][wn + ni * 16 + fr][fq * 8];
            bl[ni] = *(half8*)&sB[1][wn + ni * 16 + fr][fq * 8];
        }
        #pragma unroll
        for (int mi = 0; mi < 4; ++mi) {
            half8 ah = *(half8*)&sA[0][wm + mi * 16 + fr][fq * 8];
            half8 al = *(half8*)&sA[1][wm + mi * 16 + fr][fq * 8];
            #pragma unroll
            for (int ni = 0; ni < 4; ++ni) {
                acc[mi][ni] = __builtin_amdgcn_mfma_f32_16x16x32_f16(ah, bh[ni], acc[mi][ni], 0, 0, 0);
                acc[mi][ni] = __builtin_amdgcn_mfma_f32_16x16x32_f16(ah, bl[ni], acc[mi][ni], 0, 0, 0);
                acc[mi][ni] = __builtin_amdgcn_mfma_f32_16x16x32_f16(al, bh[ni], acc[mi][ni], 0, 0, 0);
            }
        }
    }

    // epilogue: C/D layout col=lane&15, row=quad*4+reg
    #pragma unroll
    for (int ni = 0; ni < 4; ++ni) {
        int gc = col0 + wn + ni * 16 + fr;
        float bv = bias ? bias[gc] : 0.f;
        #pragma unroll
        for (int mi = 0; mi < 4; ++mi) {
            #pragma unroll
            for (int r = 0; r < 4; ++r) {
                int gr = row0 + wm + mi * 16 + fq * 4 + r;
                if (gr >= M) continue;
                float v = acc[mi][ni][r] + bv;
                if (relu) v = (v > 0.f) ? v : 0.f;
                size_t idx = (size_t)gr * N + gc;
                if (split) {
                    _Float16 hh = (_Float16)v;
                    Chi[idx] = hh;
                    Clo[idx] = (_Float16)(v - (float)hh);
                } else {
                    Cf[idx] = v;
                }
            }
        }
    }
}

// ---------------- head: out[M x 4] = (Yh+Yl)[M x 512] @ Wo[512 x 4] + bo ----------------
__global__ __launch_bounds__(256) void k_head(const _Float16* __restrict__ Yh,
                                              const _Float16* __restrict__ Yl,
                                              const float* __restrict__ Wo,
                                              const float* __restrict__ bo,
                                              float* __restrict__ out, int M) {
    int node = blockIdx.x * 4 + (threadIdx.x >> 6);
    int lane = threadIdx.x & 63;
    if (node >= M) return;
    size_t base = (size_t)node * 512 + lane * 8;
    half8 hv = *(const half8*)(Yh + base);
    half8 lv = *(const half8*)(Yl + base);
    float a0 = 0.f, a1 = 0.f, a2 = 0.f, a3 = 0.f;
    #pragma unroll
    for (int i = 0; i < 8; i++) {
        float y = (float)hv[i] + (float)lv[i];
        float4 wv = *(const float4*)(Wo + (size_t)(lane * 8 + i) * 4);
        a0 += y * wv.x; a1 += y * wv.y;
        a2 += y * wv.z; a3 += y * wv.w;
    }
    #pragma unroll
    for (int off = 32; off > 0; off >>= 1) {
        a0 += __shfl_down(a0, off);
        a1 += __shfl_down(a1, off);
        a2 += __shfl_down(a2, off);
        a3 += __shfl_down(a3, off);
    }
    if (lane == 0) {
        float4 o;
        o.x = a0 + bo[0]; o.y = a1 + bo[1]; o.z = a2 + bo[2]; o.w = a3 + bo[3];
        *(float4*)(out + (size_t)node * 4) = o;
    }
}

extern "C" void kernel_launch(void* const* d_in, const int* in_sizes, int n_in,
                              void* d_out, int out_size, void* d_ws, size_t ws_size,
                              hipStream_t stream) {
    const float* x    = (const float*)d_in[0];
    const int*   eidx = (const int*)d_in[1];
    const float* cW   = (const float*)d_in[2];
    const float* caS  = (const float*)d_in[3];
    const float* caD  = (const float*)d_in[4];
    const float* cB   = (const float*)d_in[5];
    const float* W0   = (const float*)d_in[6];
    const float* b0   = (const float*)d_in[7];
    const float* W1   = (const float*)d_in[8];
    const float* b1   = (const float*)d_in[9];
    const float* W2   = (const float*)d_in[10];
    const float* b2   = (const float*)d_in[11];
    const float* Wo   = (const float*)d_in[12];
    const float* bo   = (const float*)d_in[13];
    (void)in_sizes; (void)n_in; (void)out_size;

    const int* esrc = eidx;
    const int* edst = eidx + NE;
    float* out = (float*)d_out;

    // ---- workspace bump allocator (256B aligned) ----
    char* w = (char*)d_ws;
    auto alloc = [&](size_t bytes) -> char* {
        char* p = w;
        w += (bytes + 255) & ~(size_t)255;
        return p;
    };
    _Float16* x0h  = (_Float16*)alloc((size_t)NN * 128 * 2);
    _Float16* x0l  = (_Float16*)alloc((size_t)NN * 128 * 2);
    _Float16* xh   = (_Float16*)alloc((size_t)NN * 128 * 2);
    _Float16* xl   = (_Float16*)alloc((size_t)NN * 128 * 2);
    float* hbuf    = (float*)alloc((size_t)NN * 128 * 4);
    float* ssrc    = (float*)alloc((size_t)NN * 4);
    float* sdst    = (float*)alloc((size_t)NN * 4);
    int*   counts  = (int*)  alloc((size_t)NN * 4);
    int*   offs    = (int*)  alloc((size_t)(NN + 1) * 4);
    int*   cursor  = (int*)  alloc((size_t)NN * 4);
    int*   csr     = (int*)  alloc((size_t)NET * 4);
    int*   part    = (int*)  alloc((size_t)SCAN_NB * 4);
    _Float16* cwh  = (_Float16*)alloc(3 * 128 * 128 * 2);
    _Float16* cwl  = (_Float16*)alloc(3 * 128 * 128 * 2);
    _Float16* w0h  = (_Float16*)alloc(512 * 128 * 2);
    _Float16* w0l  = (_Float16*)alloc(512 * 128 * 2);
    _Float16* w1h  = (_Float16*)alloc(512 * 512 * 2);
    _Float16* w1l  = (_Float16*)alloc(512 * 512 * 2);
    _Float16* w2h  = (_Float16*)alloc(512 * 512 * 2);
    _Float16* w2l  = (_Float16*)alloc(512 * 512 * 2);

    size_t used = (size_t)(w - (char*)d_ws);
    size_t rem = (ws_size > used) ? (ws_size - used) : 0;
    int chunk = (int)(rem / (4 * 512 * sizeof(_Float16)));
    if (chunk > NN) chunk = NN;
    if (chunk > 128) chunk &= ~127;
    if (chunk < 1) chunk = 1;
    _Float16* Y0h = (_Float16*)alloc((size_t)chunk * 512 * 2);
    _Float16* Y0l = (_Float16*)alloc((size_t)chunk * 512 * 2);
    _Float16* Y1h = (_Float16*)alloc((size_t)chunk * 512 * 2);
    _Float16* Y1l = (_Float16*)alloc((size_t)chunk * 512 * 2);

    auto gemm = [&](const _Float16* Ah, const _Float16* Al,
                    const _Float16* Bh, const _Float16* Bl,
                    const float* bias, float* Cf, _Float16* Ch, _Float16* Cl,
                    int M, int N, int K, int relu, int split) {
        dim3 g(N / 128, (M + 127) / 128);
        k_mgemm<<<g, 256, 0, stream>>>(Ah, Al, Bh, Bl, bias, Cf, Ch, Cl, M, N, K, relu, split);
    };

    // ---- prep: split x, transpose+split weights ----
    k_split<<<2048, 256, 0, stream>>>(x, x0h, x0l, NN * 128);
    for (int L = 0; L < 3; ++L)
        k_prepw<<<dim3(128 / 32, 128 / 32), 256, 0, stream>>>(
            cW + (size_t)L * 128 * 128, cwh + (size_t)L * 128 * 128, cwl + (size_t)L * 128 * 128, 128, 128);
    k_prepw<<<dim3(512 / 32, 128 / 32), 256, 0, stream>>>(W0, w0h, w0l, 128, 512);
    k_prepw<<<dim3(512 / 32, 512 / 32), 256, 0, stream>>>(W1, w1h, w1l, 512, 512);
    k_prepw<<<dim3(512 / 32, 512 / 32), 256, 0, stream>>>(W2, w2h, w2l, 512, 512);

    // ---- build CSR once ----
    hipMemsetAsync(counts, 0, (size_t)NN * 4, stream);
    int eblocks = (NET + 255) / 256;
    k_count <<<eblocks, 256, 0, stream>>>(edst, counts);
    k_scan1 <<<SCAN_NB, 256, 0, stream>>>(counts, part);
    k_scan2 <<<1, 256, 0, stream>>>(part, offs);
    k_scan3 <<<SCAN_NB, 256, 0, stream>>>(counts, part, offs, cursor);
    k_scatter<<<eblocks, 256, 0, stream>>>(esrc, edst, cursor, csr);

    // ---- 3 GAT layers ----
    for (int L = 0; L < 3; ++L) {
        const _Float16* Ah = (L == 0) ? x0h : xh;
        const _Float16* Al = (L == 0) ? x0l : xl;
        gemm(Ah, Al, cwh + (size_t)L * 128 * 128, cwl + (size_t)L * 128 * 128,
             nullptr, hbuf, nullptr, nullptr, NN, 128, 128, 0, 0);
        k_scalars  <<<NN / 4, 256, 0, stream>>>(hbuf, caS + L * 128, caD + L * 128, ssrc, sdst);
        k_aggregate<<<NN / 4, 256, 0, stream>>>(hbuf, ssrc, sdst, offs, csr, cB + L * 128, xh, xl);
    }

    // ---- MLP head (chunked over nodes) ----
    for (int m0 = 0; m0 < NN; m0 += chunk) {
        int cm = imin(chunk, NN - m0);
        gemm(xh + (size_t)m0 * 128, xl + (size_t)m0 * 128, w0h, w0l, b0,
             nullptr, Y0h, Y0l, cm, 512, 128, 1, 1);
        gemm(Y0h, Y0l, w1h, w1l, b1, nullptr, Y1h, Y1l, cm, 512, 512, 1, 1);
        gemm(Y1h, Y1l, w2h, w2l, b2, nullptr, Y0h, Y0l, cm, 512, 512, 1, 1);
        k_head<<<(cm + 3) / 4, 256, 0, stream>>>(Y0h, Y0l, Wo, bo, out + (size_t)m0 * 4, cm);
    }
}

// Round 7
// 986.293 us; speedup vs baseline: 1.7319x; 1.0214x over previous
//
#include <hip/hip_runtime.h>
#include <hip/hip_bf16.h>

#define NN 50000
#define NE 800000
#define NET (NE + NN)
#define SCAN_NB ((NN + 255) / 256)   // 196

static inline int imin(int a, int b) { return a < b ? a : b; }

typedef _Float16 half8 __attribute__((ext_vector_type(8)));
typedef float f32x4 __attribute__((ext_vector_type(4)));

// ---------------- CSR build (graph constant across layers) ----------------
__global__ void k_count(const int* __restrict__ edst, int* __restrict__ counts) {
    int e = blockIdx.x * blockDim.x + threadIdx.x;
    if (e >= NET) return;
    int d = (e < NE) ? edst[e] : (e - NE);   // self loops appended
    atomicAdd(&counts[d], 1);
}

// hierarchical exclusive scan of counts[NN] -> offs/cursor (3 stages)
__global__ __launch_bounds__(256) void k_scan1(const int* __restrict__ counts,
                                               int* __restrict__ part) {
    __shared__ int s[256];
    int t = threadIdx.x, i = blockIdx.x * 256 + t;
    s[t] = (i < NN) ? counts[i] : 0;
    __syncthreads();
    for (int off = 128; off > 0; off >>= 1) {
        if (t < off) s[t] += s[t + off];
        __syncthreads();
    }
    if (t == 0) part[blockIdx.x] = s[0];
}

__global__ __launch_bounds__(256) void k_scan2(int* __restrict__ part, int* __restrict__ offs) {
    __shared__ int s[256];
    int t = threadIdx.x;
    int v = (t < SCAN_NB) ? part[t] : 0;
    s[t] = v;
    __syncthreads();
    for (int off = 1; off < 256; off <<= 1) {
        int a = (t >= off) ? s[t - off] : 0;
        __syncthreads();
        s[t] += a;
        __syncthreads();
    }
    if (t < SCAN_NB) part[t] = s[t] - v;     // exclusive block offsets
    if (t == 255) offs[NN] = s[255];         // total (= NET)
}

__global__ __launch_bounds__(256) void k_scan3(const int* __restrict__ counts,
                                               const int* __restrict__ part,
                                               int* __restrict__ offs, int* __restrict__ cursor) {
    __shared__ int s[256];
    int t = threadIdx.x, i = blockIdx.x * 256 + t;
    int v = (i < NN) ? counts[i] : 0;
    s[t] = v;
    __syncthreads();
    for (int off = 1; off < 256; off <<= 1) {
        int a = (t >= off) ? s[t - off] : 0;
        __syncthreads();
        s[t] += a;
        __syncthreads();
    }
    if (i < NN) {
        int e = part[blockIdx.x] + s[t] - v;
        offs[i] = e;
        cursor[i] = e;
    }
}

__global__ void k_scatter(const int* __restrict__ esrc, const int* __restrict__ edst,
                          int* __restrict__ cursor, int* __restrict__ csr_src) {
    int e = blockIdx.x * blockDim.x + threadIdx.x;
    if (e >= NET) return;
    int s, d;
    if (e < NE) { s = esrc[e]; d = edst[e]; } else { s = e - NE; d = s; }
    int pos = atomicAdd(&cursor[d], 1);
    csr_src[pos] = s;
}

// ---------------- split fp32 -> f16 hi/lo pair ----------------
__global__ void k_split(const float* __restrict__ in, _Float16* __restrict__ hi,
                        _Float16* __restrict__ lo, int n) {
    int i = blockIdx.x * blockDim.x + threadIdx.x;
    int st = gridDim.x * blockDim.x;
    for (; i < n; i += st) {
        float v = in[i];
        _Float16 h = (_Float16)v;
        hi[i] = h;
        lo[i] = (_Float16)(v - (float)h);
    }
}

// ---------------- transpose + split weights: W[K][N] -> T[N][K] hi/lo (LDS-tiled) ----
__global__ __launch_bounds__(256) void k_prepw(const float* __restrict__ W,
                                               _Float16* __restrict__ Th,
                                               _Float16* __restrict__ Tl, int K, int N) {
    __shared__ float tile[32][33];
    int tx = threadIdx.x & 31, ty = threadIdx.x >> 5;
    int n0 = blockIdx.x * 32, k0 = blockIdx.y * 32;
    #pragma unroll
    for (int r = ty; r < 32; r += 8)
        tile[r][tx] = W[(size_t)(k0 + r) * N + n0 + tx];   // coalesced read
    __syncthreads();
    #pragma unroll
    for (int r = ty; r < 32; r += 8) {
        int n = n0 + r, k = k0 + tx;
        float v = tile[tx][r];
        _Float16 h = (_Float16)v;
        Th[(size_t)n * K + k] = h;                          // coalesced 64B segments
        Tl[(size_t)n * K + k] = (_Float16)(v - (float)h);
    }
}

// ---------------- per-node attention scalars: s = h . a ----------------
__global__ void k_scalars(const float* __restrict__ h, const float* __restrict__ a_src,
                          const float* __restrict__ a_dst, float* __restrict__ s_src,
                          float* __restrict__ s_dst) {
    int node = blockIdx.x * 4 + (threadIdx.x >> 6);
    int lane = threadIdx.x & 63;
    if (node >= NN) return;
    const float* hr = h + (size_t)node * 128;
    float h0 = hr[lane], h1 = hr[lane + 64];
    float ps = h0 * a_src[lane] + h1 * a_src[lane + 64];
    float pd = h0 * a_dst[lane] + h1 * a_dst[lane + 64];
    #pragma unroll
    for (int off = 32; off > 0; off >>= 1) {
        ps += __shfl_down(ps, off);
        pd += __shfl_down(pd, off);
    }
    if (lane == 0) { s_src[node] = ps; s_dst[node] = pd; }
}

// ---------------- fused segment-softmax + aggregate + bias + leaky ----------------
__global__ void k_aggregate(const float* __restrict__ h, const float* __restrict__ s_src,
                            const float* __restrict__ s_dst, const int* __restrict__ offs,
                            const int* __restrict__ csr_src, const float* __restrict__ bias,
                            _Float16* __restrict__ xh, _Float16* __restrict__ xl) {
    int node = blockIdx.x * 4 + (threadIdx.x >> 6);
    int lane = threadIdx.x & 63;
    if (node >= NN) return;
    int p = offs[node], pe = offs[node + 1];
    float sd = s_dst[node];
    float den = 0.f, acc0 = 0.f, acc1 = 0.f;
    for (; p < pe; ++p) {
        int src = csr_src[p];                 // broadcast read
        float e = s_src[src] + sd;
        e = (e > 0.f) ? e : 0.2f * e;         // leaky_relu(e, 0.2)
        float wgt = __expf(e);
        den += wgt;
        const float* hr = h + (size_t)src * 128;
        acc0 += wgt * hr[lane];
        acc1 += wgt * hr[lane + 64];
    }
    float inv = 1.f / den;                    // self-loop guarantees den > 0
    float v0 = acc0 * inv + bias[lane];
    float v1 = acc1 * inv + bias[lane + 64];
    v0 = (v0 > 0.f) ? v0 : 0.2f * v0;
    v1 = (v1 > 0.f) ? v1 : 0.2f * v1;
    _Float16 h0 = (_Float16)v0, h1 = (_Float16)v1;
    size_t base = (size_t)node * 128;
    xh[base + lane]      = h0;
    xl[base + lane]      = (_Float16)(v0 - (float)h0);
    xh[base + lane + 64] = h1;
    xl[base + lane + 64] = (_Float16)(v1 - (float)h1);
}

// ---------------- split-f16 MFMA GEMM ----------------
// C[M][N] = act(A[M][K] @ B^T[N][K] + bias), A,B as f16 hi/lo pairs,
// A·B ≈ Ahi·Bhi + Ahi·Blo + Alo·Bhi (fp32 MFMA accumulate).
// 128x128 tile, 4 waves (2x2), each wave 64x64 = 4x4 of 16x16x32 MFMA. BK=32.
// 1D grid with XCD-aware tile order: bid -> g = (bid&7)*per + (bid>>3), tiles
// row-major. Under HW round-robin block->XCD placement, each XCD processes a
// contiguous tile run, so all col-tiles of a row-tile hit the same XCD's L2
// (A-panel fetched once). Locality-only heuristic: wrong mapping = no harm.
__global__ __launch_bounds__(256) void k_mgemm(
    const _Float16* __restrict__ Ahi, const _Float16* __restrict__ Alo,
    const _Float16* __restrict__ Bhi, const _Float16* __restrict__ Blo,
    const float* __restrict__ bias, float* __restrict__ Cf,
    _Float16* __restrict__ Chi, _Float16* __restrict__ Clo,
    int M, int N, int K, int relu, int split, int nx, int ntiles)
{
    __shared__ _Float16 sA[2][128][40];   // stride 40: <=2-way bank aliasing (free)
    __shared__ _Float16 sB[2][128][40];

    int bid = blockIdx.x;
    int per = (ntiles + 7) >> 3;
    int g = (bid & 7) * per + (bid >> 3);
    if (g >= ntiles) return;
    int col0 = (g % nx) * 128;
    int row0 = (g / nx) * 128;

    int t = threadIdx.x;
    int w = t >> 6, lane = t & 63;
    int wm = (w & 1) * 64, wn = (w >> 1) * 64;
    int fr = lane & 15;
    int fq = lane >> 4;

    int srow = t >> 2;
    int scol = (t & 3) * 8;

    f32x4 acc[4][4];
    #pragma unroll
    for (int i = 0; i < 4; i++)
        #pragma unroll
        for (int j = 0; j < 4; j++) acc[i][j] = (f32x4){0.f, 0.f, 0.f, 0.f};

    for (int k0 = 0; k0 < K; k0 += 32) {
        if (k0) __syncthreads();
        #pragma unroll
        for (int c = 0; c < 2; ++c) {
            int r = srow + c * 64;
            int ga = row0 + r;
            half8 vh = {}, vl = {};
            if (ga < M) {
                vh = *(const half8*)(Ahi + (size_t)ga * K + k0 + scol);
                vl = *(const half8*)(Alo + (size_t)ga * K + k0 + scol);
            }
            *(half8*)&sA[0][r][scol] = vh;
            *(half8*)&sA[1][r][scol] = vl;
            int gb = col0 + r;
            *(half8*)&sB[0][r][scol] = *(const half8*)(Bhi + (size_t)gb * K + k0 + scol);
            *(half8*)&sB[1][r][scol] = *(const half8*)(Blo + (size_t)gb * K + k0 + scol);
        }
        __syncthreads();

        half8 bh[4], bl[4];
        #pragma unroll
        for (int ni = 0; ni < 4; ++ni) {
            bh[ni] = *(half8*)&sB[0][wn + ni * 16 + fr][fq * 8];
            bl[ni] = *(half8*)&sB[1][wn + ni * 16 + fr][fq * 8];
        }
        #pragma unroll
        for (int mi = 0; mi < 4; ++mi) {
            half8 ah = *(half8*)&sA[0][wm + mi * 16 + fr][fq * 8];
            half8 al = *(half8*)&sA[1][wm + mi * 16 + fr][fq * 8];
            #pragma unroll
            for (int ni = 0; ni < 4; ++ni) {
                acc[mi][ni] = __builtin_amdgcn_mfma_f32_16x16x32_f16(ah, bh[ni], acc[mi][ni], 0, 0, 0);
                acc[mi][ni] = __builtin_amdgcn_mfma_f32_16x16x32_f16(ah, bl[ni], acc[mi][ni], 0, 0, 0);
                acc[mi][ni] = __builtin_amdgcn_mfma_f32_16x16x32_f16(al, bh[ni], acc[mi][ni], 0, 0, 0);
            }
        }
    }

    // epilogue: C/D layout col=lane&15, row=quad*4+reg
    #pragma unroll
    for (int ni = 0; ni < 4; ++ni) {
        int gc = col0 + wn + ni * 16 + fr;
        float bv = bias ? bias[gc] : 0.f;
        #pragma unroll
        for (int mi = 0; mi < 4; ++mi) {
            #pragma unroll
            for (int r = 0; r < 4; ++r) {
                int gr = row0 + wm + mi * 16 + fq * 4 + r;
                if (gr >= M) continue;
                float v = acc[mi][ni][r] + bv;
                if (relu) v = (v > 0.f) ? v : 0.f;
                size_t idx = (size_t)gr * N + gc;
                if (split) {
                    _Float16 hh = (_Float16)v;
                    Chi[idx] = hh;
                    Clo[idx] = (_Float16)(v - (float)hh);
                } else {
                    Cf[idx] = v;
                }
            }
        }
    }
}

// ---------------- head: out[M x 4] = (Yh+Yl)[M x 512] @ Wo[512 x 4] + bo ----------------
__global__ __launch_bounds__(256) void k_head(const _Float16* __restrict__ Yh,
                                              const _Float16* __restrict__ Yl,
                                              const float* __restrict__ Wo,
                                              const float* __restrict__ bo,
                                              float* __restrict__ out, int M) {
    int node = blockIdx.x * 4 + (threadIdx.x >> 6);
    int lane = threadIdx.x & 63;
    if (node >= M) return;
    size_t base = (size_t)node * 512 + lane * 8;
    half8 hv = *(const half8*)(Yh + base);
    half8 lv = *(const half8*)(Yl + base);
    float a0 = 0.f, a1 = 0.f, a2 = 0.f, a3 = 0.f;
    #pragma unroll
    for (int i = 0; i < 8; i++) {
        float y = (float)hv[i] + (float)lv[i];
        float4 wv = *(const float4*)(Wo + (size_t)(lane * 8 + i) * 4);
        a0 += y * wv.x; a1 += y * wv.y;
        a2 += y * wv.z; a3 += y * wv.w;
    }
    #pragma unroll
    for (int off = 32; off > 0; off >>= 1) {
        a0 += __shfl_down(a0, off);
        a1 += __shfl_down(a1, off);
        a2 += __shfl_down(a2, off);
        a3 += __shfl_down(a3, off);
    }
    if (lane == 0) {
        float4 o;
        o.x = a0 + bo[0]; o.y = a1 + bo[1]; o.z = a2 + bo[2]; o.w = a3 + bo[3];
        *(float4*)(out + (size_t)node * 4) = o;
    }
}

extern "C" void kernel_launch(void* const* d_in, const int* in_sizes, int n_in,
                              void* d_out, int out_size, void* d_ws, size_t ws_size,
                              hipStream_t stream) {
    const float* x    = (const float*)d_in[0];
    const int*   eidx = (const int*)d_in[1];
    const float* cW   = (const float*)d_in[2];
    const float* caS  = (const float*)d_in[3];
    const float* caD  = (const float*)d_in[4];
    const float* cB   = (const float*)d_in[5];
    const float* W0   = (const float*)d_in[6];
    const float* b0   = (const float*)d_in[7];
    const float* W1   = (const float*)d_in[8];
    const float* b1   = (const float*)d_in[9];
    const float* W2   = (const float*)d_in[10];
    const float* b2   = (const float*)d_in[11];
    const float* Wo   = (const float*)d_in[12];
    const float* bo   = (const float*)d_in[13];
    (void)in_sizes; (void)n_in; (void)out_size;

    const int* esrc = eidx;
    const int* edst = eidx + NE;
    float* out = (float*)d_out;

    // ---- workspace bump allocator (256B aligned) ----
    char* w = (char*)d_ws;
    auto alloc = [&](size_t bytes) -> char* {
        char* p = w;
        w += (bytes + 255) & ~(size_t)255;
        return p;
    };
    _Float16* x0h  = (_Float16*)alloc((size_t)NN * 128 * 2);
    _Float16* x0l  = (_Float16*)alloc((size_t)NN * 128 * 2);
    _Float16* xh   = (_Float16*)alloc((size_t)NN * 128 * 2);
    _Float16* xl   = (_Float16*)alloc((size_t)NN * 128 * 2);
    float* hbuf    = (float*)alloc((size_t)NN * 128 * 4);
    float* ssrc    = (float*)alloc((size_t)NN * 4);
    float* sdst    = (float*)alloc((size_t)NN * 4);
    int*   counts  = (int*)  alloc((size_t)NN * 4);
    int*   offs    = (int*)  alloc((size_t)(NN + 1) * 4);
    int*   cursor  = (int*)  alloc((size_t)NN * 4);
    int*   csr     = (int*)  alloc((size_t)NET * 4);
    int*   part    = (int*)  alloc((size_t)SCAN_NB * 4);
    _Float16* cwh  = (_Float16*)alloc(3 * 128 * 128 * 2);
    _Float16* cwl  = (_Float16*)alloc(3 * 128 * 128 * 2);
    _Float16* w0h  = (_Float16*)alloc(512 * 128 * 2);
    _Float16* w0l  = (_Float16*)alloc(512 * 128 * 2);
    _Float16* w1h  = (_Float16*)alloc(512 * 512 * 2);
    _Float16* w1l  = (_Float16*)alloc(512 * 512 * 2);
    _Float16* w2h  = (_Float16*)alloc(512 * 512 * 2);
    _Float16* w2l  = (_Float16*)alloc(512 * 512 * 2);

    size_t used = (size_t)(w - (char*)d_ws);
    size_t rem = (ws_size > used) ? (ws_size - used) : 0;
    int chunk = (int)(rem / (4 * 512 * sizeof(_Float16)));
    if (chunk > NN) chunk = NN;
    if (chunk > 128) chunk &= ~127;
    if (chunk < 1) chunk = 1;
    _Float16* Y0h = (_Float16*)alloc((size_t)chunk * 512 * 2);
    _Float16* Y0l = (_Float16*)alloc((size_t)chunk * 512 * 2);
    _Float16* Y1h = (_Float16*)alloc((size_t)chunk * 512 * 2);
    _Float16* Y1l = (_Float16*)alloc((size_t)chunk * 512 * 2);

    auto gemm = [&](const _Float16* Ah, const _Float16* Al,
                    const _Float16* Bh, const _Float16* Bl,
                    const float* bias, float* Cf, _Float16* Ch, _Float16* Cl,
                    int M, int N, int K, int relu, int split) {
        int nx = N / 128;
        int ntiles = nx * ((M + 127) / 128);
        int nb = ((ntiles + 7) / 8) * 8;
        k_mgemm<<<nb, 256, 0, stream>>>(Ah, Al, Bh, Bl, bias, Cf, Ch, Cl,
                                        M, N, K, relu, split, nx, ntiles);
    };

    // ---- prep: split x, transpose+split weights ----
    k_split<<<2048, 256, 0, stream>>>(x, x0h, x0l, NN * 128);
    for (int L = 0; L < 3; ++L)
        k_prepw<<<dim3(128 / 32, 128 / 32), 256, 0, stream>>>(
            cW + (size_t)L * 128 * 128, cwh + (size_t)L * 128 * 128, cwl + (size_t)L * 128 * 128, 128, 128);
    k_prepw<<<dim3(512 / 32, 128 / 32), 256, 0, stream>>>(W0, w0h, w0l, 128, 512);
    k_prepw<<<dim3(512 / 32, 512 / 32), 256, 0, stream>>>(W1, w1h, w1l, 512, 512);
    k_prepw<<<dim3(512 / 32, 512 / 32), 256, 0, stream>>>(W2, w2h, w2l, 512, 512);

    // ---- build CSR once ----
    hipMemsetAsync(counts, 0, (size_t)NN * 4, stream);
    int eblocks = (NET + 255) / 256;
    k_count <<<eblocks, 256, 0, stream>>>(edst, counts);
    k_scan1 <<<SCAN_NB, 256, 0, stream>>>(counts, part);
    k_scan2 <<<1, 256, 0, stream>>>(part, offs);
    k_scan3 <<<SCAN_NB, 256, 0, stream>>>(counts, part, offs, cursor);
    k_scatter<<<eblocks, 256, 0, stream>>>(esrc, edst, cursor, csr);

    // ---- 3 GAT layers ----
    for (int L = 0; L < 3; ++L) {
        const _Float16* Ah = (L == 0) ? x0h : xh;
        const _Float16* Al = (L == 0) ? x0l : xl;
        gemm(Ah, Al, cwh + (size_t)L * 128 * 128, cwl + (size_t)L * 128 * 128,
             nullptr, hbuf, nullptr, nullptr, NN, 128, 128, 0, 0);
        k_scalars  <<<NN / 4, 256, 0, stream>>>(hbuf, caS + L * 128, caD + L * 128, ssrc, sdst);
        k_aggregate<<<NN / 4, 256, 0, stream>>>(hbuf, ssrc, sdst, offs, csr, cB + L * 128, xh, xl);
    }

    // ---- MLP head (chunked over nodes) ----
    for (int m0 = 0; m0 < NN; m0 += chunk) {
        int cm = imin(chunk, NN - m0);
        gemm(xh + (size_t)m0 * 128, xl + (size_t)m0 * 128, w0h, w0l, b0,
             nullptr, Y0h, Y0l, cm, 512, 128, 1, 1);
        gemm(Y0h, Y0l, w1h, w1l, b1, nullptr, Y1h, Y1l, cm, 512, 512, 1, 1);
        gemm(Y1h, Y1l, w2h, w2l, b2, nullptr, Y0h, Y0l, cm, 512, 512, 1, 1);
        k_head<<<(cm + 3) / 4, 256, 0, stream>>>(Y0h, Y0l, Wo, bo, out + (size_t)m0 * 4, cm);
    }
}